// Round 4
// baseline (183.103 us; speedup 1.0000x reference)
//
#include <hip/hip_runtime.h>

// Problem constants
#define BB 256
#define PP 128
#define KK 16
#define HH 128
#define OO 256
#define EE 18      // 2*(C+F)
#define XCH 10     // C + F + 1 (coords, feats, mask)
#define BIGD 1000000000.0f
#define GPT 4      // points per chunk (= waves per block)
#define PITER 4    // chunks per block
#define NBLK 2048  // 2048 x 4 chunks = 8192 chunks = 32768 points

typedef __bf16 bf16x8 __attribute__((ext_vector_type(8)));
typedef __bf16 bf16x4 __attribute__((ext_vector_type(4)));
typedef float  f32x4  __attribute__((ext_vector_type(4)));

// ---------------------------------------------------------------------------
// Kernel 1: pack W2 and W1 into bf16 MFMA fragment order.
// W2p (B-frag, 16x16x32): [ct 16][ks 4][lane 64][j 8], elem = W2[ks*32+(l>>4)*8+j][ct*16+(l&15)]
// W1p (A-frag for h1^T = W1^T @ edge^T): [nt 8][lane 64][j 8],
//   elem = W1[k][nt*16+(l&15)] for k=(l>>4)*8+j < 18, else 0 (K padded to 32).
// ---------------------------------------------------------------------------
__global__ __launch_bounds__(256) void pack_w_kernel(const float* __restrict__ W1,
                                                     const float* __restrict__ W2,
                                                     __bf16* __restrict__ W2p,
                                                     __bf16* __restrict__ W1p) {
    const int t = blockIdx.x * 256 + threadIdx.x;  // 0 .. 36863
    if (t < 32768) {
        const int j  = t & 7;
        const int l  = (t >> 3) & 63;
        const int ks = (t >> 9) & 3;
        const int ct = t >> 11;
        const int row = ks * 32 + ((l >> 4) * 8) + j;
        const int col = ct * 16 + (l & 15);
        W2p[t] = (__bf16)W2[row * OO + col];
    } else {
        const int t2 = t - 32768;  // 0 .. 4095
        const int j  = t2 & 7;
        const int l  = (t2 >> 3) & 63;
        const int nt = t2 >> 9;
        const int k  = ((l >> 4) * 8) + j;
        const int n  = nt * 16 + (l & 15);
        W1p[t2] = (k < EE) ? (__bf16)W1[k * HH + n] : (__bf16)0.0f;
    }
}

// ---------------------------------------------------------------------------
// Kernel 2: fully-fused EdgeConv: per-block KNN + edge-MLP (all-MFMA).
//
// CHUNKED revision: r1/r3 dispatch-rate triangulation (r1: 8192 WG / 63.3us
// = 129 WG/us = the CP's WG launch rate; r3's 512-thr WGs halved the rate)
// shows the kernel is workgroup-launch-bound, not resource-bound. r2's
// persistent fix was right but spilled loop-carried regs (hoisted wf +
// center row) -> +110MB scratch traffic. This version: the EXACT r1 63us
// body (GPT=4, 256 thr) in a 4-chunk loop with ZERO loop-carried state --
// wf/center-row/masks reloaded per iteration (L1/L2-hot), only `it` lives
// across iterations. 2048 WGs -> dispatch floor ~19us, 8 WG/CU resident.
//  - trailing __syncthreads: iter t's GEMM2 reads of sh1A vs iter t+1's
//    epilogue-1 writes (cross-wave). Skip path is block-uniform, no LDS.
// Numerics identical to the 128.7us version (same op order everywhere).
// ---------------------------------------------------------------------------
__global__ __launch_bounds__(256) void mlp_kernel(const float* __restrict__ x,
                                                  const __bf16* __restrict__ W1p,
                                                  const float* __restrict__ b1,
                                                  const __bf16* __restrict__ W2p,
                                                  const float* __restrict__ b2,
                                                  float* __restrict__ out) {
    __shared__ __bf16 sh1A[16 * 64 * 8];  // [ks*4+g][lane][j], 16 KB
    __shared__ int    sknn[GPT][KK];      // per-wave winner slots

    const int tid = threadIdx.x;
    const int lane = tid & 63;
    const int w = tid >> 6;
    const int quad = lane >> 4;
    const int lcol = lane & 15;

    for (int it = 0; it < PITER; ++it) {
        const int cidx = blockIdx.x * PITER + it;   // consecutive chunks/block
        const int pbase = cidx * GPT;
        const int bidx = pbase >> 7;
        const int i0 = pbase & (PP - 1);
        const float* xb = x + (size_t)bidx * PP * XCH;
        float* outrow = out + (size_t)pbase * (OO + 1);

        // masks straight from x (L1-hot)
        const float mq = xb[(i0 + quad) * XCH + (XCH - 1)];
        const int i = i0 + w;

        if (__all(mq == 0.0f)) {
            // out is re-poisoned before every launch: must write zeros
            for (int o = tid; o < GPT * (OO + 1); o += 256) outrow[o] = 0.0f;
            continue;  // block-uniform: no barrier on this path
        }

        // ---- GEMM1 A-fragments (reloaded per iter: NO loop-carried regs) ----
        bf16x8 wf[8];
#pragma unroll
        for (int nt = 0; nt < 8; ++nt)
            wf[nt] = *(const bf16x8*)&W1p[(size_t)((nt * 64 + lane) * 8)];

        // ---- center row (wave-uniform address), independent of KNN ----
        const float* ci = xb + i * XCH;
        const float2 a01 = *(const float2*)(ci + 0);
        const float2 a23 = *(const float2*)(ci + 2);
        const float2 a45 = *(const float2*)(ci + 4);
        const float2 a67 = *(const float2*)(ci + 6);
        const float  a8  = ci[8];
        const float  mw  = ci[XCH - 1];   // this wave's point mask

        // ================= KNN: wave w selects 16 neighbors of point i ======
        // RADIX-4 select over 128 candidates (lane l owns j=l and j=l+64).
        // key = (d_bits << 7) | j : unique, ascending key order ==
        // lexicographic (d, j) == jax.lax.top_k's stable order (d >= 0 so
        // fp32 bits are monotone as uint). Self is the unique d=0 min == the
        // dropped "nearest", so exclude it and select the top-16 SET. dist2
        // uses __fmul_rn/__fadd_rn to match numpy bit-exact.
        if (mw != 0.0f) {   // wave-uniform
            const float cix = a01.x;
            const float ciy = a01.y;

            const int j0 = lane, j1 = lane + 64;
            float d0, d1;
            {
                const float2 c0 = *(const float2*)(xb + j0 * XCH);
                const float m0 = xb[j0 * XCH + (XCH - 1)];
                float dx = cix - c0.x, dy = ciy - c0.y;
                d0 = __fadd_rn(__fmul_rn(dx, dx), __fmul_rn(dy, dy));
                if (m0 <= 0.0f || j0 == i) d0 = BIGD;
            }
            {
                const float2 c1 = *(const float2*)(xb + j1 * XCH);
                const float m1 = xb[j1 * XCH + (XCH - 1)];
                float dx = cix - c1.x, dy = ciy - c1.y;
                d1 = __fadd_rn(__fmul_rn(dx, dx), __fmul_rn(dy, dy));
                if (m1 <= 0.0f || j1 == i) d1 = BIGD;
            }

            const unsigned d0b = __float_as_uint(d0);
            const unsigned d1b = __float_as_uint(d1);

            unsigned long long A0 = ~0ull, A1 = ~0ull, W0 = 0ull, W1 = 0ull;
            int need = KK;
            int asz = 2 * 64;   // |A|

            auto step = [&](unsigned long long q0, unsigned long long q1) {
                const unsigned long long z0 = A0 & q0;
                const unsigned long long z1 = A1 & q1;
                const int c = __popcll(z0) + __popcll(z1);
                if (c == need) { W0 |= z0; W1 |= z1; A0 = A1 = 0ull; need = 0; }
                else if (c > need) { A0 = z0; A1 = z1; asz = c; }
                else { W0 |= z0; W1 |= z1; need -= c; A0 &= ~z0; A1 &= ~z1; asz -= c; }
            };

            // phase A: radix-4 digits over d bits (30,29),(28,27),...,(2,1)
#pragma unroll 1
            for (int t = 14; t >= 0; --t) {
                const unsigned dg0 = (d0b >> (2 * t + 1)) & 3u;
                const unsigned dg1 = (d1b >> (2 * t + 1)) & 3u;
                const unsigned long long p0_0  = __ballot(dg0 == 0u);
                const unsigned long long p1_0  = __ballot(dg1 == 0u);
                const unsigned long long p0_01 = __ballot(dg0 <= 1u);
                const unsigned long long p1_01 = __ballot(dg1 <= 1u);
                const unsigned long long p0_02 = __ballot(dg0 <= 2u);
                const unsigned long long p1_02 = __ballot(dg1 <= 2u);
                const unsigned long long z0_0  = A0 & p0_0,  z1_0  = A1 & p1_0;
                const unsigned long long z0_01 = A0 & p0_01, z1_01 = A1 & p1_01;
                const unsigned long long z0_02 = A0 & p0_02, z1_02 = A1 & p1_02;
                const int c0  = __popcll(z0_0)  + __popcll(z1_0);
                const int c01 = __popcll(z0_01) + __popcll(z1_01);
                const int c02 = __popcll(z0_02) + __popcll(z1_02);
                if (c0 >= need) {
                    A0 = z0_0; A1 = z1_0; asz = c0;
                } else if (c01 >= need) {
                    W0 |= z0_0; W1 |= z1_0; need -= c0;
                    A0 = z0_01 & ~p0_0; A1 = z1_01 & ~p1_0; asz = c01 - c0;
                } else if (c02 >= need) {
                    W0 |= z0_01; W1 |= z1_01; need -= c01;
                    A0 = z0_02 & ~p0_01; A1 = z1_02 & ~p1_01; asz = c02 - c01;
                } else {
                    W0 |= z0_02; W1 |= z1_02; need -= c02;
                    A0 &= ~p0_02; A1 &= ~p1_02; asz -= c02;
                }
                if (asz == need) { W0 |= A0; W1 |= A1; A0 = A1 = 0ull; need = 0; break; }
            }
            // phase A': last d bit (bit 0)
            if (need) {
                const unsigned long long q0 = __ballot((d0b & 1u) == 0u);
                const unsigned long long q1 = __ballot((d1b & 1u) == 0u);
                step(q0, q1);
            }
            // phase B: index bits 6..0 (j0 = lane, j1 = lane+64): const masks
            if (need) step(~0ull, 0ull);  // bit 6: all j0 are 0, all j1 are 1
            {
                const unsigned long long M5 = 0x00000000FFFFFFFFull;
                const unsigned long long M4 = 0x0000FFFF0000FFFFull;
                const unsigned long long M3 = 0x00FF00FF00FF00FFull;
                const unsigned long long M2 = 0x0F0F0F0F0F0F0F0Full;
                const unsigned long long M1 = 0x3333333333333333ull;
                const unsigned long long M0 = 0x5555555555555555ull;
                if (need) step(M5, M5);
                if (need) step(M4, M4);
                if (need) step(M3, M3);
                if (need) step(M2, M2);
                if (need) step(M1, M1);
                if (need) step(M0, M0);
            }
            W0 |= A0; W1 |= A1;  // keys unique => remaining actives = the rest

            unsigned int mb0 = __builtin_amdgcn_mbcnt_lo((unsigned)(W0 & 0xffffffffull), 0u);
            mb0 = __builtin_amdgcn_mbcnt_hi((unsigned)(W0 >> 32), mb0);
            unsigned int mb1 = __builtin_amdgcn_mbcnt_lo((unsigned)(W1 & 0xffffffffull), 0u);
            mb1 = __builtin_amdgcn_mbcnt_hi((unsigned)(W1 >> 32), mb1);
            const int base1 = __popcll(W0);

            if ((W0 >> lane) & 1ull) sknn[w][mb0] = j0;
            if ((W1 >> lane) & 1ull) sknn[w][base1 + mb1] = j1;
        } else {
            if (lane < KK) sknn[w][lane] = 0;  // dummy valid indices (masked)
        }
        // NO barrier: wave w reads only its own sknn[w] (lgkmcnt-ordered)

        // ============ edge build -> GEMM1 B-fragment (registers only) =======
        // this thread: point g=w, neighbor slot lcol, channel block quad
        const int jn = sknn[w][lcol];
        const float* cj = xb + jn * XCH;
        const float2 n01 = *(const float2*)(cj + 0);
        const float2 n23 = *(const float2*)(cj + 2);
        const float2 n45 = *(const float2*)(cj + 4);
        const float2 n67 = *(const float2*)(cj + 6);
        const float  n8  = cj[8];

        float v[8];
#pragma unroll
        for (int e = 0; e < 8; ++e) v[e] = 0.0f;
        if (quad == 0) {           // channels 0..7 = center ch 0..7
            v[0] = a01.x; v[1] = a01.y; v[2] = a23.x; v[3] = a23.y;
            v[4] = a45.x; v[5] = a45.y; v[6] = a67.x; v[7] = a67.y;
        } else if (quad == 1) {    // ch 8 = center ch8; ch 9..15 = diff 0..6
            v[0] = a8;
            v[1] = n01.x - a01.x; v[2] = n01.y - a01.y;
            v[3] = n23.x - a23.x; v[4] = n23.y - a23.y;
            v[5] = n45.x - a45.x; v[6] = n45.y - a45.y;
            v[7] = n67.x - a67.x;
        } else if (quad == 2) {    // ch 16 = diff ch7; ch 17 = diff ch8
            v[0] = n67.y - a67.y;
            v[1] = n8 - a8;
        }                          // quad 3: zero padding (K 18 -> 32)

        bf16x8 ef;
#pragma unroll
        for (int e = 0; e < 8; ++e) ef[e] = (__bf16)v[e];

        // ---- GEMM1 (MFMA): h1^T tiles; A = wf, B = ef ----
        const f32x4 z4 = {0.0f, 0.0f, 0.0f, 0.0f};
        f32x4 h[8];
#pragma unroll
        for (int nt = 0; nt < 8; ++nt)
            h[nt] = __builtin_amdgcn_mfma_f32_16x16x32_bf16(wf[nt], ef, z4, 0, 0, 0);

        // ---- epilogue 1: relu(+b1), write bf16 into GEMM2 A-frag order ----
        // b1 read directly as broadcast float4 (L1-hot, no LDS staging).
#pragma unroll
        for (int nt = 0; nt < 8; ++nt) {
            const int ks = nt >> 1;
            const int lp = (((nt * 2 + (quad >> 1)) & 3) << 4) | lcol;
            const f32x4 b1v = *(const f32x4*)&b1[nt * 16 + quad * 4];
            bf16x4 hv;
#pragma unroll
            for (int r = 0; r < 4; ++r)
                hv[r] = (__bf16)fmaxf(h[nt][r] + b1v[r], 0.0f);
            *(bf16x4*)&sh1A[((ks * GPT + w) * 64 + lp) * 8 + (quad & 1) * 4] = hv;
        }
        __syncthreads();

        // ---- GEMM2 (MFMA): h2[64][256] = relu(h1 @ W2 + b2), fused K-mean --
        // Two ct-halves: acc live-set 32 f32 regs; af re-read per half.
        const float mscale = mq * (1.0f / KK);
#pragma unroll
        for (int ch = 0; ch < 2; ++ch) {
            f32x4 acc[GPT][2];
#pragma unroll
            for (int g = 0; g < GPT; ++g) { acc[g][0] = z4; acc[g][1] = z4; }

#pragma unroll
            for (int ks = 0; ks < 4; ++ks) {
                bf16x8 af[GPT], bfr[2];
#pragma unroll
                for (int g = 0; g < GPT; ++g)
                    af[g] = *(const bf16x8*)&sh1A[((ks * GPT + g) * 64 + lane) * 8];
#pragma unroll
                for (int c = 0; c < 2; ++c) {
                    const int ct = ch * 2 + c;
                    bfr[c] = *(const bf16x8*)&W2p[(size_t)((((w * 4 + ct) * 4 + ks) * 64 + lane) * 8)];
                }
#pragma unroll
                for (int g = 0; g < GPT; ++g)
#pragma unroll
                    for (int c = 0; c < 2; ++c)
                        acc[g][c] = __builtin_amdgcn_mfma_f32_16x16x32_bf16(
                            af[g], bfr[c], acc[g][c], 0, 0, 0);
            }

            // ---- epilogue 2: relu(+b2), K-sum = tile column sum ----
            // C layout: col=lcol, row=quad*4+r; tile g's 16 rows = point g's
            // K neighbors. 4 rows in-lane, then fold quads (xor 16, 32).
#pragma unroll
            for (int c = 0; c < 2; ++c) {
                const int ct = ch * 2 + c;
                const int col = w * 64 + ct * 16 + lcol;
                const float bc = b2[col];
                float val = 0.0f;
#pragma unroll
                for (int g = 0; g < GPT; ++g) {
                    float s = 0.0f;
#pragma unroll
                    for (int r = 0; r < 4; ++r) s += fmaxf(acc[g][c][r] + bc, 0.0f);
                    s += __shfl_xor(s, 16, 64);
                    s += __shfl_xor(s, 32, 64);
                    if (quad == g) val = s;   // lane (quad=g, lcol) keeps pt g
                }
                outrow[(size_t)quad * (OO + 1) + col] = val * mscale;
            }
        }
        if (tid < GPT) outrow[(size_t)tid * (OO + 1) + OO] = xb[(i0 + tid) * XCH + (XCH - 1)];

        // protect sh1A: iter t's GEMM2 reads vs iter t+1's epilogue-1 writes
        __syncthreads();
    }
}

extern "C" void kernel_launch(void* const* d_in, const int* in_sizes, int n_in,
                              void* d_out, int out_size, void* d_ws, size_t ws_size,
                              hipStream_t stream) {
    const float* x  = (const float*)d_in[0];
    const float* W1 = (const float*)d_in[1];
    const float* b1 = (const float*)d_in[2];
    const float* W2 = (const float*)d_in[3];
    const float* b2 = (const float*)d_in[4];
    float* out = (float*)d_out;

    __bf16* W2p = (__bf16*)d_ws;                    // 64 KB
    __bf16* W1p = (__bf16*)((char*)d_ws + 65536);   // 8 KB

    pack_w_kernel<<<144, 256, 0, stream>>>(W1, W2, W2p, W1p);

    mlp_kernel<<<NBLK, 256, 0, stream>>>(x, W1p, b1, W2p, b2, out);
}

// Round 5
// 133.087 us; speedup vs baseline: 1.3758x; 1.3758x over previous
//
#include <hip/hip_runtime.h>

// Problem constants
#define BB 256
#define PP 128
#define KK 16
#define HH 128
#define OO 256
#define EE 18      // 2*(C+F)
#define XCH 10     // C + F + 1 (coords, feats, mask)
#define BIGD 1000000000.0f
#define GPT 16     // points per WG (2 phases x 8)
#define PH 8       // points per phase
#define NBLK ((BB * PP) / GPT)  // 2048

typedef __bf16 bf16x8 __attribute__((ext_vector_type(8)));
typedef __bf16 bf16x4 __attribute__((ext_vector_type(4)));
typedef float  f32x4  __attribute__((ext_vector_type(4)));

// ---------------------------------------------------------------------------
// Kernel 1: pack W2 and W1 into bf16 MFMA fragment order.
// W2p (B-frag, 16x16x32): [ct 16][ks 4][lane 64][j 8], elem = W2[ks*32+(l>>4)*8+j][ct*16+(l&15)]
// W1p (A-frag for h1^T = W1^T @ edge^T): [nt 8][lane 64][j 8],
//   elem = W1[k][nt*16+(l&15)] for k=(l>>4)*8+j < 18, else 0 (K padded to 32).
// ---------------------------------------------------------------------------
__global__ __launch_bounds__(256) void pack_w_kernel(const float* __restrict__ W1,
                                                     const float* __restrict__ W2,
                                                     __bf16* __restrict__ W2p,
                                                     __bf16* __restrict__ W1p) {
    const int t = blockIdx.x * 256 + threadIdx.x;  // 0 .. 36863
    if (t < 32768) {
        const int j  = t & 7;
        const int l  = (t >> 3) & 63;
        const int ks = (t >> 9) & 3;
        const int ct = t >> 11;
        const int row = ks * 32 + ((l >> 4) * 8) + j;
        const int col = ct * 16 + (l & 15);
        W2p[t] = (__bf16)W2[row * OO + col];
    } else {
        const int t2 = t - 32768;  // 0 .. 4095
        const int j  = t2 & 7;
        const int l  = (t2 >> 3) & 63;
        const int nt = t2 >> 9;
        const int k  = ((l >> 4) * 8) + j;
        const int n  = nt * 16 + (l & 15);
        W1p[t2] = (k < EE) ? (__bf16)W1[k * HH + n] : (__bf16)0.0f;
    }
}

// ---------------------------------------------------------------------------
// Kernel 2: fully-fused EdgeConv: per-block KNN + edge-MLP (all-MFMA).
//
// 16-POINT / 2-PHASE revision. Evidence r1-r4: per-chunk latency is a fixed
// ~4us serial chain; throughput = residency / latency. Flat micro-WGs are
// CP-launch-rate-bound (~130 WG/us for 256-thr); in-WG serial chunk loops
// collapse residency (r2/r4: 1-2 WG/CU). This version: ONE 256-thr WG owns
// 16 points as TWO 8-point phases (no 4-deep serial loop):
//  - per wave per phase: 2 KNN selects + 2 edge-builds + 2 GEMM1s (the
//    candidate rows c0/c1/m0/m1 are loaded ONCE and shared by both selects);
//  - cooperative GEMM2 per phase: sh1A = 8 points x 128 feat bf16 (32 KB),
//    wave w owns output cols w*64..w*64+63 for all 8 points (keeps W2p
//    B-frag traffic WG-shared: 16KB/wave/phase, not per-point);
//  - grid 2048 WGs (launch floor ~16us), LDS 33KB -> 4 WG/CU,
//    __launch_bounds__(256,4) -> <=128 VGPR -> 16 waves/CU target.
// Numerics identical to the 128.7us version (same op order everywhere).
// ---------------------------------------------------------------------------
__global__ __launch_bounds__(256, 4) void mlp_kernel(const float* __restrict__ x,
                                                     const __bf16* __restrict__ W1p,
                                                     const float* __restrict__ b1,
                                                     const __bf16* __restrict__ W2p,
                                                     const float* __restrict__ b2,
                                                     float* __restrict__ out) {
    __shared__ __bf16 sh1A[4 * PH * 64 * 8];  // [ks4][g8][lane][j], 32 KB
    __shared__ int    sknn[PH][KK];           // winner slots, phase-local

    const int tid = threadIdx.x;
    const int lane = tid & 63;
    const int w = tid >> 6;
    const int quad = lane >> 4;
    const int lcol = lane & 15;

    const int pbase = blockIdx.x * GPT;
    const int bidx = pbase >> 7;
    const int i0 = pbase & (PP - 1);           // 8 WGs per batch item
    const float* xb = x + (size_t)bidx * PP * XCH;
    float* outrow = out + (size_t)pbase * (OO + 1);

    // ---- GEMM1 A-fragments: loaded once, used by both phases ----
    bf16x8 wf[8];
#pragma unroll
    for (int nt = 0; nt < 8; ++nt)
        wf[nt] = *(const bf16x8*)&W1p[(size_t)((nt * 64 + lane) * 8)];

    const f32x4 z4 = {0.0f, 0.0f, 0.0f, 0.0f};

#pragma unroll
    for (int h = 0; h < 2; ++h) {
        const int r0 = h * PH;   // first local point row of this phase

        // phase masks (same 8 values in every wave -> block-uniform predicate)
        const float mph = xb[(i0 + r0 + (lane & 7)) * XCH + (XCH - 1)];
        if (__all(mph == 0.0f)) {
            // out is re-poisoned before every launch: must write zeros
            for (int o = tid; o < PH * (OO + 1); o += 256)
                outrow[(size_t)r0 * (OO + 1) + o] = 0.0f;
            continue;  // block-uniform: no barrier on this path
        }

        // ---- candidate rows: loaded once, shared by this wave's 2 selects ----
        const int j0 = lane, j1 = lane + 64;
        const float2 c0 = *(const float2*)(xb + j0 * XCH);
        const float  m0 = xb[j0 * XCH + (XCH - 1)];
        const float2 c1 = *(const float2*)(xb + j1 * XCH);
        const float  m1 = xb[j1 * XCH + (XCH - 1)];

        // ============ KNN: wave w selects neighbors of its 2 points =========
        // RADIX-4 select over 128 candidates (lane l owns j=l and j=l+64).
        // key = (d_bits << 7) | j : unique, ascending key order ==
        // lexicographic (d, j) == jax.lax.top_k's stable order (d >= 0 so
        // fp32 bits are monotone as uint). Self is the unique d=0 min == the
        // dropped "nearest", so exclude it and select the top-16 SET. dist2
        // uses __fmul_rn/__fadd_rn to match numpy bit-exact.
#pragma unroll 1
        for (int p = 0; p < 2; ++p) {
            const int g = w * 2 + p;
            const int ip = i0 + r0 + g;
            const float2 cc = *(const float2*)(xb + ip * XCH);
            const float mwp = xb[ip * XCH + (XCH - 1)];
            if (mwp != 0.0f) {   // wave-uniform
                float d0, d1;
                {
                    float dx = cc.x - c0.x, dy = cc.y - c0.y;
                    d0 = __fadd_rn(__fmul_rn(dx, dx), __fmul_rn(dy, dy));
                    if (m0 <= 0.0f || j0 == ip) d0 = BIGD;
                }
                {
                    float dx = cc.x - c1.x, dy = cc.y - c1.y;
                    d1 = __fadd_rn(__fmul_rn(dx, dx), __fmul_rn(dy, dy));
                    if (m1 <= 0.0f || j1 == ip) d1 = BIGD;
                }

                const unsigned d0b = __float_as_uint(d0);
                const unsigned d1b = __float_as_uint(d1);

                unsigned long long A0 = ~0ull, A1 = ~0ull, W0 = 0ull, W1 = 0ull;
                int need = KK;
                int asz = 2 * 64;   // |A|

                auto step = [&](unsigned long long q0, unsigned long long q1) {
                    const unsigned long long z0 = A0 & q0;
                    const unsigned long long z1 = A1 & q1;
                    const int c = __popcll(z0) + __popcll(z1);
                    if (c == need) { W0 |= z0; W1 |= z1; A0 = A1 = 0ull; need = 0; }
                    else if (c > need) { A0 = z0; A1 = z1; asz = c; }
                    else { W0 |= z0; W1 |= z1; need -= c; A0 &= ~z0; A1 &= ~z1; asz -= c; }
                };

                // phase A: radix-4 digits over d bits (30,29),(28,27),...,(2,1)
#pragma unroll 1
                for (int t = 14; t >= 0; --t) {
                    const unsigned dg0 = (d0b >> (2 * t + 1)) & 3u;
                    const unsigned dg1 = (d1b >> (2 * t + 1)) & 3u;
                    const unsigned long long p0_0  = __ballot(dg0 == 0u);
                    const unsigned long long p1_0  = __ballot(dg1 == 0u);
                    const unsigned long long p0_01 = __ballot(dg0 <= 1u);
                    const unsigned long long p1_01 = __ballot(dg1 <= 1u);
                    const unsigned long long p0_02 = __ballot(dg0 <= 2u);
                    const unsigned long long p1_02 = __ballot(dg1 <= 2u);
                    const unsigned long long z0_0  = A0 & p0_0,  z1_0  = A1 & p1_0;
                    const unsigned long long z0_01 = A0 & p0_01, z1_01 = A1 & p1_01;
                    const unsigned long long z0_02 = A0 & p0_02, z1_02 = A1 & p1_02;
                    const int c0c  = __popcll(z0_0)  + __popcll(z1_0);
                    const int c01 = __popcll(z0_01) + __popcll(z1_01);
                    const int c02 = __popcll(z0_02) + __popcll(z1_02);
                    if (c0c >= need) {
                        A0 = z0_0; A1 = z1_0; asz = c0c;
                    } else if (c01 >= need) {
                        W0 |= z0_0; W1 |= z1_0; need -= c0c;
                        A0 = z0_01 & ~p0_0; A1 = z1_01 & ~p1_0; asz = c01 - c0c;
                    } else if (c02 >= need) {
                        W0 |= z0_01; W1 |= z1_01; need -= c01;
                        A0 = z0_02 & ~p0_01; A1 = z1_02 & ~p1_01; asz = c02 - c01;
                    } else {
                        W0 |= z0_02; W1 |= z1_02; need -= c02;
                        A0 &= ~p0_02; A1 &= ~p1_02; asz -= c02;
                    }
                    if (asz == need) { W0 |= A0; W1 |= A1; A0 = A1 = 0ull; need = 0; break; }
                }
                // phase A': last d bit (bit 0)
                if (need) {
                    const unsigned long long q0 = __ballot((d0b & 1u) == 0u);
                    const unsigned long long q1 = __ballot((d1b & 1u) == 0u);
                    step(q0, q1);
                }
                // phase B: index bits 6..0 (j0 = lane, j1 = lane+64)
                if (need) step(~0ull, 0ull);  // bit 6: all j0=0, all j1=1
                {
                    const unsigned long long M5 = 0x00000000FFFFFFFFull;
                    const unsigned long long M4 = 0x0000FFFF0000FFFFull;
                    const unsigned long long M3 = 0x00FF00FF00FF00FFull;
                    const unsigned long long M2 = 0x0F0F0F0F0F0F0F0Full;
                    const unsigned long long M1 = 0x3333333333333333ull;
                    const unsigned long long M0 = 0x5555555555555555ull;
                    if (need) step(M5, M5);
                    if (need) step(M4, M4);
                    if (need) step(M3, M3);
                    if (need) step(M2, M2);
                    if (need) step(M1, M1);
                    if (need) step(M0, M0);
                }
                W0 |= A0; W1 |= A1;  // keys unique => remaining = the rest

                unsigned int mb0 = __builtin_amdgcn_mbcnt_lo((unsigned)(W0 & 0xffffffffull), 0u);
                mb0 = __builtin_amdgcn_mbcnt_hi((unsigned)(W0 >> 32), mb0);
                unsigned int mb1 = __builtin_amdgcn_mbcnt_lo((unsigned)(W1 & 0xffffffffull), 0u);
                mb1 = __builtin_amdgcn_mbcnt_hi((unsigned)(W1 >> 32), mb1);
                const int base1 = __popcll(W0);

                if ((W0 >> lane) & 1ull) sknn[g][mb0] = j0;
                if ((W1 >> lane) & 1ull) sknn[g][base1 + mb1] = j1;
            } else {
                if (lane < KK) sknn[g][lane] = 0;  // dummy valid indices
            }
        }
        // NO barrier: wave reads only its own sknn rows (DS in-order per wave)

        // ============ edge build + GEMM1 + epilogue-1, for both points ======
#pragma unroll
        for (int p = 0; p < 2; ++p) {
            const int g = w * 2 + p;
            const int ip = i0 + r0 + g;
            const int jn = sknn[g][lcol];
            const float* ciP = xb + ip * XCH;   // wave-uniform (L1-hot)
            const float* cjP = xb + jn * XCH;
            const float2 a01 = *(const float2*)(ciP + 0);
            const float2 a23 = *(const float2*)(ciP + 2);
            const float2 a45 = *(const float2*)(ciP + 4);
            const float2 a67 = *(const float2*)(ciP + 6);
            const float  a8  = ciP[8];
            const float2 n01 = *(const float2*)(cjP + 0);
            const float2 n23 = *(const float2*)(cjP + 2);
            const float2 n45 = *(const float2*)(cjP + 4);
            const float2 n67 = *(const float2*)(cjP + 6);
            const float  n8  = cjP[8];

            float v[8];
#pragma unroll
            for (int e = 0; e < 8; ++e) v[e] = 0.0f;
            if (quad == 0) {           // channels 0..7 = center ch 0..7
                v[0] = a01.x; v[1] = a01.y; v[2] = a23.x; v[3] = a23.y;
                v[4] = a45.x; v[5] = a45.y; v[6] = a67.x; v[7] = a67.y;
            } else if (quad == 1) {    // ch 8 = center ch8; 9..15 = diff 0..6
                v[0] = a8;
                v[1] = n01.x - a01.x; v[2] = n01.y - a01.y;
                v[3] = n23.x - a23.x; v[4] = n23.y - a23.y;
                v[5] = n45.x - a45.x; v[6] = n45.y - a45.y;
                v[7] = n67.x - a67.x;
            } else if (quad == 2) {    // ch 16 = diff ch7; ch 17 = diff ch8
                v[0] = n67.y - a67.y;
                v[1] = n8 - a8;
            }                          // quad 3: zero padding (K 18 -> 32)

            bf16x8 ef;
#pragma unroll
            for (int e = 0; e < 8; ++e) ef[e] = (__bf16)v[e];

            // GEMM1 (MFMA): h1^T tiles; A = wf, B = ef
            f32x4 hh[8];
#pragma unroll
            for (int nt = 0; nt < 8; ++nt)
                hh[nt] = __builtin_amdgcn_mfma_f32_16x16x32_bf16(wf[nt], ef, z4, 0, 0, 0);

            // epilogue 1: relu(+b1), bf16 write into GEMM2 A-frag order
#pragma unroll
            for (int nt = 0; nt < 8; ++nt) {
                const int ks = nt >> 1;
                const int lp = (((nt * 2 + (quad >> 1)) & 3) << 4) | lcol;
                const f32x4 b1v = *(const f32x4*)&b1[nt * 16 + quad * 4];
                bf16x4 hv;
#pragma unroll
                for (int r = 0; r < 4; ++r)
                    hv[r] = (__bf16)fmaxf(hh[nt][r] + b1v[r], 0.0f);
                *(bf16x4*)&sh1A[((ks * PH + g) * 64 + lp) * 8 + (quad & 1) * 4] = hv;
            }
        }
        __syncthreads();

        // ---- GEMM2 (MFMA): 8 points x 256 cols, wave w owns cols w*64.. ----
        // g-halves x ct-pairs: acc live-set 32 f32 regs per sub-block.
#pragma unroll
        for (int gg = 0; gg < 2; ++gg) {
#pragma unroll
            for (int ch = 0; ch < 2; ++ch) {
                f32x4 acc[4][2];
#pragma unroll
                for (int gi = 0; gi < 4; ++gi) { acc[gi][0] = z4; acc[gi][1] = z4; }

#pragma unroll
                for (int ks = 0; ks < 4; ++ks) {
                    bf16x8 af[4], bfr[2];
#pragma unroll
                    for (int gi = 0; gi < 4; ++gi)
                        af[gi] = *(const bf16x8*)&sh1A[((ks * PH + gg * 4 + gi) * 64 + lane) * 8];
#pragma unroll
                    for (int c = 0; c < 2; ++c)
                        bfr[c] = *(const bf16x8*)&W2p[(size_t)((((w * 4 + ch * 2 + c) * 4 + ks) * 64 + lane) * 8)];
#pragma unroll
                    for (int gi = 0; gi < 4; ++gi)
#pragma unroll
                        for (int c = 0; c < 2; ++c)
                            acc[gi][c] = __builtin_amdgcn_mfma_f32_16x16x32_bf16(
                                af[gi], bfr[c], acc[gi][c], 0, 0, 0);
                }

                // epilogue 2: relu(+b2), K-sum = tile column sum via shuffles
                // tile gi's 16 rows = point (r0+gg*4+gi)'s K neighbors.
#pragma unroll
                for (int c = 0; c < 2; ++c) {
                    const int col = w * 64 + (ch * 2 + c) * 16 + lcol;
                    const float bc = b2[col];
                    float val = 0.0f;
#pragma unroll
                    for (int gi = 0; gi < 4; ++gi) {
                        float s = 0.0f;
#pragma unroll
                        for (int r = 0; r < 4; ++r) s += fmaxf(acc[gi][c][r] + bc, 0.0f);
                        s += __shfl_xor(s, 16, 64);
                        s += __shfl_xor(s, 32, 64);
                        if (quad == gi) val = s;   // lane (quad=gi,lcol) keeps
                    }
                    const float mp = xb[(i0 + r0 + gg * 4 + quad) * XCH + (XCH - 1)];
                    outrow[(size_t)(r0 + gg * 4 + quad) * (OO + 1) + col] = val * (mp * (1.0f / KK));
                }
            }
        }
        if (tid < PH)
            outrow[(size_t)(r0 + tid) * (OO + 1) + OO] = xb[(i0 + r0 + tid) * XCH + (XCH - 1)];

        // protect sh1A: this phase's GEMM2 reads vs next phase's epi-1 writes
        __syncthreads();
    }
}

extern "C" void kernel_launch(void* const* d_in, const int* in_sizes, int n_in,
                              void* d_out, int out_size, void* d_ws, size_t ws_size,
                              hipStream_t stream) {
    const float* x  = (const float*)d_in[0];
    const float* W1 = (const float*)d_in[1];
    const float* b1 = (const float*)d_in[2];
    const float* W2 = (const float*)d_in[3];
    const float* b2 = (const float*)d_in[4];
    float* out = (float*)d_out;

    __bf16* W2p = (__bf16*)d_ws;                    // 64 KB
    __bf16* W1p = (__bf16*)((char*)d_ws + 65536);   // 8 KB

    pack_w_kernel<<<144, 256, 0, stream>>>(W1, W2, W2p, W1p);

    mlp_kernel<<<NBLK, 256, 0, stream>>>(x, W1p, b1, W2p, b2, out);
}

// Round 6
// 126.606 us; speedup vs baseline: 1.4462x; 1.0512x over previous
//
#include <hip/hip_runtime.h>

// Problem constants
#define BB 256
#define PP 128
#define KK 16
#define HH 128
#define OO 256
#define EE 18      // 2*(C+F)
#define XCH 10     // C + F + 1 (coords, feats, mask)
#define BIGD 1000000000.0f
#define GPT 8      // points per WG (4 waves x 2 points/wave, ONE phase)
#define NBLK ((BB * PP) / GPT)  // 4096

typedef __bf16 bf16x8 __attribute__((ext_vector_type(8)));
typedef __bf16 bf16x4 __attribute__((ext_vector_type(4)));
typedef float  f32x4  __attribute__((ext_vector_type(4)));
typedef unsigned long long ull;

// ---------------------------------------------------------------------------
// Kernel 1: pack W2 and W1 into bf16 MFMA fragment order.
// W2p (B-frag, 16x16x32): [ct 16][ks 4][lane 64][j 8], elem = W2[ks*32+(l>>4)*8+j][ct*16+(l&15)]
// W1p (A-frag for h1^T = W1^T @ edge^T): [nt 8][lane 64][j 8],
//   elem = W1[k][nt*16+(l&15)] for k=(l>>4)*8+j < 18, else 0 (K padded to 32).
// ---------------------------------------------------------------------------
__global__ __launch_bounds__(256) void pack_w_kernel(const float* __restrict__ W1,
                                                     const float* __restrict__ W2,
                                                     __bf16* __restrict__ W2p,
                                                     __bf16* __restrict__ W1p) {
    const int t = blockIdx.x * 256 + threadIdx.x;  // 0 .. 36863
    if (t < 32768) {
        const int j  = t & 7;
        const int l  = (t >> 3) & 63;
        const int ks = (t >> 9) & 3;
        const int ct = t >> 11;
        const int row = ks * 32 + ((l >> 4) * 8) + j;
        const int col = ct * 16 + (l & 15);
        W2p[t] = (__bf16)W2[row * OO + col];
    } else {
        const int t2 = t - 32768;  // 0 .. 4095
        const int j  = t2 & 7;
        const int l  = (t2 >> 3) & 63;
        const int nt = t2 >> 9;
        const int k  = ((l >> 4) * 8) + j;
        const int n  = nt * 16 + (l & 15);
        W1p[t2] = (k < EE) ? (__bf16)W1[k * HH + n] : (__bf16)0.0f;
    }
}

// ---------------------------------------------------------------------------
// Kernel 2: fully-fused EdgeConv: per-block KNN + edge-MLP (all-MFMA).
//
// BATCHED-SELECT revision. Model from r1/r3/r5: wave throughput ~520
// waves/us chip-wide (r1's 63us IS its 32768-wave floor); serial in-WG
// phases inflate lifetime below launch parity (r5), loop-carried state
// spills (r2/r5: WRITE 33->48MB). Fix: HALVE the wave count (4096 WGs x 4
// waves, 8 points/WG) with each wave running TWO KNN selects BATCHED through
// one radix round-loop (independent state machines, ballots back-to-back per
// round -> ~1.3x one select's latency, not 2x). One phase, one barrier, no
// loop-carried state. GEMM2 is the r5 8-point cooperative form (B-frags
// WG-shared). LDS 33KB -> 4 WG/CU, launch_bounds(256,4) -> <=128 VGPR.
// Numerics identical to the 128.7us version (same op order everywhere).
// ---------------------------------------------------------------------------
__global__ __launch_bounds__(256, 4) void mlp_kernel(const float* __restrict__ x,
                                                     const __bf16* __restrict__ W1p,
                                                     const float* __restrict__ b1,
                                                     const __bf16* __restrict__ W2p,
                                                     const float* __restrict__ b2,
                                                     float* __restrict__ out) {
    __shared__ __bf16 sh1A[4 * GPT * 64 * 8];  // [ks4][g8][lane][j], 32 KB
    __shared__ int    sknn[GPT][KK];           // per-point winner slots

    const int tid = threadIdx.x;
    const int lane = tid & 63;
    const int w = tid >> 6;          // 0..3
    const int quad = lane >> 4;
    const int lcol = lane & 15;

    const int pbase = blockIdx.x * GPT;
    const int bidx = pbase >> 7;
    const int i0 = pbase & (PP - 1);           // 16 WGs per batch item
    const float* xb = x + (size_t)bidx * PP * XCH;
    float* outrow = out + (size_t)pbase * (OO + 1);

    // all-8 masks (same values in every wave -> block-uniform predicate)
    const float mph = xb[(i0 + (lane & 7)) * XCH + (XCH - 1)];
    if (__all(mph == 0.0f)) {
        // out is re-poisoned before every launch: must write zeros
        for (int o = tid; o < GPT * (OO + 1); o += 256) outrow[o] = 0.0f;
        return;  // block-uniform: no barrier mismatch
    }

    // ---- candidate rows: loaded once, shared by this wave's 2 selects ----
    const int j0 = lane, j1 = lane + 64;
    const float2 c0 = *(const float2*)(xb + j0 * XCH);
    const float  m0 = xb[j0 * XCH + (XCH - 1)];
    const float2 c1 = *(const float2*)(xb + j1 * XCH);
    const float  m1 = xb[j1 * XCH + (XCH - 1)];

    // ---- this wave's 2 points ----
    const int gA = w * 2, gB = w * 2 + 1;
    const int iA = i0 + gA, iB = i0 + gB;
    const float2 ccA = *(const float2*)(xb + iA * XCH);
    const float  mA  = xb[iA * XCH + (XCH - 1)];
    const float2 ccB = *(const float2*)(xb + iB * XCH);
    const float  mB  = xb[iB * XCH + (XCH - 1)];

    // ---- GEMM1 A-fragments (issued now; consumed after the selects) ----
    bf16x8 wf[8];
#pragma unroll
    for (int nt = 0; nt < 8; ++nt)
        wf[nt] = *(const bf16x8*)&W1p[(size_t)((nt * 64 + lane) * 8)];

    // ================= KNN: 2 selects batched through one radix loop =======
    // RADIX-4 select over 128 candidates (lane l owns j=l and j=l+64).
    // key = (d_bits << 7) | j : unique, ascending key order == lexicographic
    // (d, j) == jax.lax.top_k's stable order (d >= 0 so fp32 bits are
    // monotone as uint). Self is the unique d=0 min == the dropped "nearest",
    // so exclude it and select the top-16 SET (order irrelevant: outputs are
    // K-sums). dist2 uses __fmul_rn/__fadd_rn to match numpy bit-exact.
    // Two independent state machines share each round's latency (ballots
    // issued back-to-back; per-point scalar guards + fast-exit).
    unsigned db0[2], db1[2];
    {
        float dx, dy, d;
        dx = ccA.x - c0.x; dy = ccA.y - c0.y;
        d = __fadd_rn(__fmul_rn(dx, dx), __fmul_rn(dy, dy));
        if (m0 <= 0.0f || j0 == iA) d = BIGD;
        db0[0] = __float_as_uint(d);
        dx = ccA.x - c1.x; dy = ccA.y - c1.y;
        d = __fadd_rn(__fmul_rn(dx, dx), __fmul_rn(dy, dy));
        if (m1 <= 0.0f || j1 == iA) d = BIGD;
        db1[0] = __float_as_uint(d);
        dx = ccB.x - c0.x; dy = ccB.y - c0.y;
        d = __fadd_rn(__fmul_rn(dx, dx), __fmul_rn(dy, dy));
        if (m0 <= 0.0f || j0 == iB) d = BIGD;
        db0[1] = __float_as_uint(d);
        dx = ccB.x - c1.x; dy = ccB.y - c1.y;
        d = __fadd_rn(__fmul_rn(dx, dx), __fmul_rn(dy, dy));
        if (m1 <= 0.0f || j1 == iB) d = BIGD;
        db1[1] = __float_as_uint(d);
    }

    const bool act[2] = {mA != 0.0f, mB != 0.0f};   // wave-uniform
    ull A0[2], A1[2], W0[2], W1g[2];
    int need[2], asz[2];
#pragma unroll
    for (int p = 0; p < 2; ++p) {
        A0[p] = ~0ull; A1[p] = ~0ull; W0[p] = 0ull; W1g[p] = 0ull;
        need[p] = act[p] ? KK : 0;
        asz[p] = 128;
    }

    // phase A: radix-4 digits over d bits (30,29),(28,27),...,(2,1)
#pragma unroll 1
    for (int t = 14; t >= 0; --t) {
#pragma unroll
        for (int p = 0; p < 2; ++p) {
            if (need[p]) {   // wave-uniform guard
                const unsigned dg0 = (db0[p] >> (2 * t + 1)) & 3u;
                const unsigned dg1 = (db1[p] >> (2 * t + 1)) & 3u;
                const ull p0_0  = __ballot(dg0 == 0u);
                const ull p1_0  = __ballot(dg1 == 0u);
                const ull p0_01 = __ballot(dg0 <= 1u);
                const ull p1_01 = __ballot(dg1 <= 1u);
                const ull p0_02 = __ballot(dg0 <= 2u);
                const ull p1_02 = __ballot(dg1 <= 2u);
                const ull z0_0  = A0[p] & p0_0,  z1_0  = A1[p] & p1_0;
                const ull z0_01 = A0[p] & p0_01, z1_01 = A1[p] & p1_01;
                const ull z0_02 = A0[p] & p0_02, z1_02 = A1[p] & p1_02;
                const int c0c = __popcll(z0_0)  + __popcll(z1_0);
                const int c01 = __popcll(z0_01) + __popcll(z1_01);
                const int c02 = __popcll(z0_02) + __popcll(z1_02);
                if (c0c >= need[p]) {
                    A0[p] = z0_0; A1[p] = z1_0; asz[p] = c0c;
                } else if (c01 >= need[p]) {
                    W0[p] |= z0_0; W1g[p] |= z1_0; need[p] -= c0c;
                    A0[p] = z0_01 & ~p0_0; A1[p] = z1_01 & ~p1_0; asz[p] = c01 - c0c;
                } else if (c02 >= need[p]) {
                    W0[p] |= z0_01; W1g[p] |= z1_01; need[p] -= c01;
                    A0[p] = z0_02 & ~p0_01; A1[p] = z1_02 & ~p1_01; asz[p] = c02 - c01;
                } else {
                    W0[p] |= z0_02; W1g[p] |= z1_02; need[p] -= c02;
                    A0[p] &= ~p0_02; A1[p] &= ~p1_02; asz[p] -= c02;
                }
                if (asz[p] == need[p]) {
                    W0[p] |= A0[p]; W1g[p] |= A1[p];
                    A0[p] = A1[p] = 0ull; need[p] = 0;
                }
            }
        }
        if (!(need[0] | need[1])) break;
    }
    // phases A' (last d bit) + B (index bits 6..0), per point
#pragma unroll
    for (int p = 0; p < 2; ++p) {
        auto stepP = [&](ull q0, ull q1) {
            const ull z0 = A0[p] & q0;
            const ull z1 = A1[p] & q1;
            const int c = __popcll(z0) + __popcll(z1);
            if (c == need[p]) { W0[p] |= z0; W1g[p] |= z1; A0[p] = A1[p] = 0ull; need[p] = 0; }
            else if (c > need[p]) { A0[p] = z0; A1[p] = z1; asz[p] = c; }
            else { W0[p] |= z0; W1g[p] |= z1; need[p] -= c; A0[p] &= ~z0; A1[p] &= ~z1; asz[p] -= c; }
        };
        if (need[p]) {
            const ull q0 = __ballot((db0[p] & 1u) == 0u);
            const ull q1 = __ballot((db1[p] & 1u) == 0u);
            stepP(q0, q1);
        }
        if (need[p]) stepP(~0ull, 0ull);  // index bit 6: all j0=0, all j1=1
        {
            const ull M5 = 0x00000000FFFFFFFFull;
            const ull M4 = 0x0000FFFF0000FFFFull;
            const ull M3 = 0x00FF00FF00FF00FFull;
            const ull M2 = 0x0F0F0F0F0F0F0F0Full;
            const ull M1 = 0x3333333333333333ull;
            const ull M0 = 0x5555555555555555ull;
            if (need[p]) stepP(M5, M5);
            if (need[p]) stepP(M4, M4);
            if (need[p]) stepP(M3, M3);
            if (need[p]) stepP(M2, M2);
            if (need[p]) stepP(M1, M1);
            if (need[p]) stepP(M0, M0);
        }
        W0[p] |= A0[p]; W1g[p] |= A1[p];  // keys unique => remaining = rest

        const int g = w * 2 + p;
        if (act[p]) {
            unsigned int mb0 = __builtin_amdgcn_mbcnt_lo((unsigned)(W0[p] & 0xffffffffull), 0u);
            mb0 = __builtin_amdgcn_mbcnt_hi((unsigned)(W0[p] >> 32), mb0);
            unsigned int mb1 = __builtin_amdgcn_mbcnt_lo((unsigned)(W1g[p] & 0xffffffffull), 0u);
            mb1 = __builtin_amdgcn_mbcnt_hi((unsigned)(W1g[p] >> 32), mb1);
            const int base1 = __popcll(W0[p]);
            if ((W0[p] >> lane) & 1ull) sknn[g][mb0] = j0;
            if ((W1g[p] >> lane) & 1ull) sknn[g][base1 + mb1] = j1;
        } else {
            if (lane < KK) sknn[g][lane] = 0;  // dummy valid indices (masked)
        }
    }
    // NO barrier: wave reads only its own sknn rows (DS in-order per wave)

    // ============ edge build + GEMM1 + epilogue-1, for both points ==========
    const f32x4 z4 = {0.0f, 0.0f, 0.0f, 0.0f};
#pragma unroll
    for (int p = 0; p < 2; ++p) {
        const int g = w * 2 + p;
        const int ip = i0 + g;
        const int jn = sknn[g][lcol];
        const float* ciP = xb + ip * XCH;   // wave-uniform (L1-hot)
        const float* cjP = xb + jn * XCH;
        const float2 a01 = *(const float2*)(ciP + 0);
        const float2 a23 = *(const float2*)(ciP + 2);
        const float2 a45 = *(const float2*)(ciP + 4);
        const float2 a67 = *(const float2*)(ciP + 6);
        const float  a8  = ciP[8];
        const float2 n01 = *(const float2*)(cjP + 0);
        const float2 n23 = *(const float2*)(cjP + 2);
        const float2 n45 = *(const float2*)(cjP + 4);
        const float2 n67 = *(const float2*)(cjP + 6);
        const float  n8  = cjP[8];

        float v[8];
#pragma unroll
        for (int e = 0; e < 8; ++e) v[e] = 0.0f;
        if (quad == 0) {           // channels 0..7 = center ch 0..7
            v[0] = a01.x; v[1] = a01.y; v[2] = a23.x; v[3] = a23.y;
            v[4] = a45.x; v[5] = a45.y; v[6] = a67.x; v[7] = a67.y;
        } else if (quad == 1) {    // ch 8 = center ch8; 9..15 = diff 0..6
            v[0] = a8;
            v[1] = n01.x - a01.x; v[2] = n01.y - a01.y;
            v[3] = n23.x - a23.x; v[4] = n23.y - a23.y;
            v[5] = n45.x - a45.x; v[6] = n45.y - a45.y;
            v[7] = n67.x - a67.x;
        } else if (quad == 2) {    // ch 16 = diff ch7; ch 17 = diff ch8
            v[0] = n67.y - a67.y;
            v[1] = n8 - a8;
        }                          // quad 3: zero padding (K 18 -> 32)

        bf16x8 ef;
#pragma unroll
        for (int e = 0; e < 8; ++e) ef[e] = (__bf16)v[e];

        // GEMM1 (MFMA): h1^T tiles; A = wf, B = ef
        f32x4 hh[8];
#pragma unroll
        for (int nt = 0; nt < 8; ++nt)
            hh[nt] = __builtin_amdgcn_mfma_f32_16x16x32_bf16(wf[nt], ef, z4, 0, 0, 0);

        // epilogue 1: relu(+b1), bf16 write into GEMM2 A-frag order
#pragma unroll
        for (int nt = 0; nt < 8; ++nt) {
            const int ks = nt >> 1;
            const int lp = (((nt * 2 + (quad >> 1)) & 3) << 4) | lcol;
            const f32x4 b1v = *(const f32x4*)&b1[nt * 16 + quad * 4];
            bf16x4 hv;
#pragma unroll
            for (int r = 0; r < 4; ++r)
                hv[r] = (__bf16)fmaxf(hh[nt][r] + b1v[r], 0.0f);
            *(bf16x4*)&sh1A[((ks * GPT + g) * 64 + lp) * 8 + (quad & 1) * 4] = hv;
        }
    }
    __syncthreads();

    // ---- GEMM2 (MFMA): 8 points x 256 cols, wave w owns cols w*64.. -------
    // g-halves x ct-pairs: acc live-set 32 f32 regs per sub-block; B-frags
    // WG-shared (each read once per 8 points).
#pragma unroll
    for (int gg = 0; gg < 2; ++gg) {
#pragma unroll
        for (int ch = 0; ch < 2; ++ch) {
            f32x4 acc[4][2];
#pragma unroll
            for (int gi = 0; gi < 4; ++gi) { acc[gi][0] = z4; acc[gi][1] = z4; }

#pragma unroll
            for (int ks = 0; ks < 4; ++ks) {
                bf16x8 af[4], bfr[2];
#pragma unroll
                for (int gi = 0; gi < 4; ++gi)
                    af[gi] = *(const bf16x8*)&sh1A[((ks * GPT + gg * 4 + gi) * 64 + lane) * 8];
#pragma unroll
                for (int c = 0; c < 2; ++c)
                    bfr[c] = *(const bf16x8*)&W2p[(size_t)((((w * 4 + ch * 2 + c) * 4 + ks) * 64 + lane) * 8)];
#pragma unroll
                for (int gi = 0; gi < 4; ++gi)
#pragma unroll
                    for (int c = 0; c < 2; ++c)
                        acc[gi][c] = __builtin_amdgcn_mfma_f32_16x16x32_bf16(
                            af[gi], bfr[c], acc[gi][c], 0, 0, 0);
            }

            // epilogue 2: relu(+b2), K-sum = tile column sum via shuffles
            // tile gi's 16 rows = point (gg*4+gi)'s K neighbors. 4 rows
            // in-lane, fold quads (xor 16, 32); lane quad q keeps pt gg*4+q.
#pragma unroll
            for (int c = 0; c < 2; ++c) {
                const int col = w * 64 + (ch * 2 + c) * 16 + lcol;
                const float bc = b2[col];
                float val = 0.0f;
#pragma unroll
                for (int gi = 0; gi < 4; ++gi) {
                    float s = 0.0f;
#pragma unroll
                    for (int r = 0; r < 4; ++r) s += fmaxf(acc[gi][c][r] + bc, 0.0f);
                    s += __shfl_xor(s, 16, 64);
                    s += __shfl_xor(s, 32, 64);
                    if (quad == gi) val = s;   // lane (quad=gi,lcol) keeps
                }
                const float mp = xb[(i0 + gg * 4 + quad) * XCH + (XCH - 1)];
                outrow[(size_t)(gg * 4 + quad) * (OO + 1) + col] = val * (mp * (1.0f / KK));
            }
        }
    }
    if (tid < GPT)
        outrow[(size_t)tid * (OO + 1) + OO] = xb[(i0 + tid) * XCH + (XCH - 1)];
}

extern "C" void kernel_launch(void* const* d_in, const int* in_sizes, int n_in,
                              void* d_out, int out_size, void* d_ws, size_t ws_size,
                              hipStream_t stream) {
    const float* x  = (const float*)d_in[0];
    const float* W1 = (const float*)d_in[1];
    const float* b1 = (const float*)d_in[2];
    const float* W2 = (const float*)d_in[3];
    const float* b2 = (const float*)d_in[4];
    float* out = (float*)d_out;

    __bf16* W2p = (__bf16*)d_ws;                    // 64 KB
    __bf16* W1p = (__bf16*)((char*)d_ws + 65536);   // 8 KB

    pack_w_kernel<<<144, 256, 0, stream>>>(W1, W2, W2p, W1p);

    mlp_kernel<<<NBLK, 256, 0, stream>>>(x, W1p, b1, W2p, b2, out);
}